// Round 3
// baseline (146.143 us; speedup 1.0000x reference)
//
#include <hip/hip_runtime.h>
#include <hip/hip_bf16.h>

// N=32 time, 32x32 grid, C=64 (H=4 x D=16), 3x3x3 offsets (M=27), 2 layers.
// R14 = 32x32x16 MFMA restructure. Evidence: R11 (2 blk/CU) == R13 (4 blk/CU)
// at ~41us/layer -> instruction-issue bound, not latency/occupancy/L2 bound.
// Block's 32 output columns (2 cells x 16 time rows) = one 32-wide B operand:
//  - waves = 2 headpairs x 4 m-groups (was 4 heads x 2 m-groups)
//  - per (block,m): MFMA 32->16, LDS B-reads 16->8, exp 8->4, reduce 32->8,
//    per-m overhead paid by 2 waves not 4.  Biases enter via MFMA C-in.
//  - dot reduce: 32x32 C layout splits each head's 16 rows across lane
//    halves -> single v_permlane32_swap (VALU pipe).
//  - __launch_bounds__(512,2): 256-VGPR budget, no forced spill (R12 lesson).

typedef short short8_t __attribute__((ext_vector_type(8)));
typedef float floatx16 __attribute__((ext_vector_type(16)));

__device__ __forceinline__ short f2bs(float f) {
    __hip_bfloat16 h = __float2bfloat16(f);
    return *reinterpret_cast<short*>(&h);
}
__device__ __forceinline__ float bs2f(short s) {
    union { unsigned u; float f; } v;
    v.u = ((unsigned)(unsigned short)s) << 16;
    return v.f;
}
// swizzled halo addressing: rowid in [0,216), 8 chunks of 8 shorts, pitch 64
__device__ __forceinline__ int hn_idx(int rowid, int chunk) {
    return rowid * 64 + ((chunk ^ (rowid & 7)) << 3);
}
// p(lane) + p(lane^32), all lanes (VALU pipe, no DS)
__device__ __forceinline__ float half_sum(float p) {
    float a = p, b = p;
    asm("v_permlane32_swap_b32 %0, %1" : "+v"(a), "+v"(b));
    return a + b;
}

// ---------------- prep: repack weights (32x32x16 A layout) + BN sums ----------------
__global__ void prep_kernel(const float* __restrict__ Wq, const float* __restrict__ Wk,
                            const float* __restrict__ Wv, short* __restrict__ dst,
                            const float* __restrict__ x, float* __restrict__ sums) {
    if (blockIdx.x < 220) {
        int t = blockIdx.x * 256 + threadIdx.x;
        if (t >= 110 * 512) return;
        int mat  = t >> 9;
        int rem  = t & 511;
        int hp   = rem >> 8;          // headpair: A rows hp*32..hp*32+31
        int kk   = (rem >> 6) & 3;    // K-step (16 hidden dims each)
        int lane = rem & 63;
        // A[row = hp*32 + (lane&31)][k = kk*16 + (lane>>5)*8 + j] = W[k][row]
        int krow = kk * 16 + ((lane >> 5) << 3);
        int col  = hp * 32 + (lane & 31);
        const float* W;
        if (mat < 2)       W = Wq + mat * 4096;
        else if (mat < 56) W = Wk + (mat - 2) * 4096;
        else               W = Wv + (mat - 56) * 4096;
        short8_t v;
        #pragma unroll
        for (int j = 0; j < 8; ++j) v[j] = f2bs(W[(krow + j) * 64 + col]);
        *(short8_t*)&dst[(size_t)mat * 4096 + ((hp * 4 + kk) * 64 + lane) * 8] = v;
    } else {
        int bid = blockIdx.x - 220;
        int t = bid * 256 + threadIdx.x;          // 8192 threads x 3 float4
        const float4* x4 = (const float4*)x;
        float4 v0 = x4[t * 3 + 0], v1 = x4[t * 3 + 1], v2 = x4[t * 3 + 2];
        float vv[6];
        vv[0] = v0.x + v0.w + v1.z + v2.y;
        vv[1] = v0.y + v1.x + v1.w + v2.z;
        vv[2] = v0.z + v1.y + v2.x + v2.w;
        vv[3] = v0.x*v0.x + v0.w*v0.w + v1.z*v1.z + v2.y*v2.y;
        vv[4] = v0.y*v0.y + v1.x*v1.x + v1.w*v1.w + v2.z*v2.z;
        vv[5] = v0.z*v0.z + v1.y*v1.y + v2.x*v2.x + v2.w*v2.w;
        #pragma unroll
        for (int i = 0; i < 6; ++i) {
            #pragma unroll
            for (int off = 1; off < 64; off <<= 1) vv[i] += __shfl_xor(vv[i], off);
        }
        __shared__ float part[4][6];
        if ((threadIdx.x & 63) == 0) {
            #pragma unroll
            for (int i = 0; i < 6; ++i) part[threadIdx.x >> 6][i] = vv[i];
        }
        __syncthreads();
        if (threadIdx.x < 6)
            sums[bid * 8 + threadIdx.x] = part[0][threadIdx.x] + part[1][threadIdx.x] +
                                          part[2][threadIdx.x] + part[3][threadIdx.x];
    }
}

// ---------------- fused attention layer ----------------
// grid (b=16, a=32, nb=2); block 512 = 8 waves; wave = g4*2 + hp;
// hp = headpair (channels hp*32..+31); g4 = m-group: [0,7),[7,14),[14,21),[21,27).
// lane: col = lane&31 -> (ci = col>>4 cell, e = col&15 time row); h5 = lane>>5.
template <bool FIRST>
__global__ __launch_bounds__(512, 2)
void layer_fused(const float* __restrict__ x, const float* __restrict__ sums,
                 const float* __restrict__ W_in, const float* __restrict__ b_in,
                 const short* __restrict__ hbf_in, short* __restrict__ hbf_out,
                 const float* __restrict__ Wout, const float* __restrict__ bout,
                 float* __restrict__ out,
                 const short* __restrict__ wqB, const float* __restrict__ bq,
                 const short* __restrict__ wkB, const float* __restrict__ bk,
                 const short* __restrict__ wvB, const float* __restrict__ bv) {
    __shared__ short HnS[216 * 64];   // 27.6 KB; reused for state merge + hf
    __shared__ float Waux[256];
    __shared__ float bn6[6];

    const int tid = threadIdx.x;
    const int bb0 = blockIdx.x * 2, a = blockIdx.y, nb = blockIdx.z;

    if (FIRST) {
        if (tid < 3) {
            float s = 0.f, qq = 0.f;
            #pragma unroll
            for (int p = 0; p < 32; ++p) { s += sums[p * 8 + tid]; qq += sums[p * 8 + 3 + tid]; }
            float mean = s * (1.f / 32768.f);
            float var  = qq * (1.f / 32768.f) - mean * mean;
            bn6[tid]     = mean;
            bn6[3 + tid] = rsqrtf(var + 1e-5f);
        }
        if (tid < 192)      Waux[tid] = W_in[tid];
        else if (tid < 256) Waux[tid] = b_in[tid - 192];
    } else {
        if (tid < 192)      Waux[tid] = Wout[tid];
        else if (tid < 195) Waux[tid] = bout[tid - 192];
    }
    __syncthreads();

    float mean0 = 0, mean1 = 0, mean2 = 0, rs0 = 0, rs1 = 0, rs2 = 0;
    if (FIRST) {
        mean0 = bn6[0]; mean1 = bn6[1]; mean2 = bn6[2];
        rs0 = bn6[3]; rs1 = bn6[4]; rs2 = bn6[5];
    }

    // ---- stage halo: 216 rows x 8 chunks of 8 bf16 (unchanged) ----
    for (int id = tid; id < 1728; id += 512) {
        int rowid = id >> 3, cc = id & 7;
        int r = rowid % 18;
        int rw = rowid / 18;
        int spa = rw >> 2, jcol = rw & 3;
        int aa = a + spa - 1, bb = bb0 + jcol - 1;
        int n  = nb * 16 + r - 1;
        short8_t v = {0, 0, 0, 0, 0, 0, 0, 0};
        if ((unsigned)n < 32u && (unsigned)aa < 32u && (unsigned)bb < 32u) {
            int cell = (n * 32 + aa) * 32 + bb;
            if (FIRST) {
                float xn0 = (x[cell*3+0] - mean0) * rs0;
                float xn1 = (x[cell*3+1] - mean1) * rs1;
                float xn2 = (x[cell*3+2] - mean2) * rs2;
                #pragma unroll
                for (int j = 0; j < 8; ++j) {
                    int c = cc * 8 + j;
                    float h = Waux[192+c] + xn0*Waux[c] + xn1*Waux[64+c] + xn2*Waux[128+c];
                    v[j] = f2bs(h);
                }
            } else {
                v = *(const short8_t*)&hbf_in[cell * 64 + cc * 8];
            }
        }
        *(short8_t*)&HnS[hn_idx(rowid, cc)] = v;
    }
    __syncthreads();

    const int lane = tid & 63;
    const int wv8  = tid >> 6;
    const int hp   = wv8 & 1;        // headpair
    const int g4   = wv8 >> 1;       // m-group
    const int col  = lane & 31;
    const int e    = col & 15;
    const int ci   = col >> 4;
    const int h5   = lane >> 5;

    // spatial validity
    unsigned amask = 0;
    #pragma unroll
    for (int d = 0; d < 3; ++d) if ((unsigned)(a + d - 1) < 32u) amask |= 1u << d;
    const bool vbL = (unsigned)(bb0 - 1) < 32u;   // jcol 0
    const bool vbR = (unsigned)(bb0 + 2) < 32u;   // jcol 3
    const unsigned vmask = (ci == 0) ? ((vbL ? 1u : 0u) | 2u | 4u)
                                     : (1u | 2u | (vbR ? 4u : 0u));

    const int elane = e + ci * 18;   // per-lane halo-row offset

    // ---- Q projection (center cell per col): 4 chained 32x32x16 MFMAs ----
    floatx16 qv;
    {
        const float* bqp = &bq[hp * 32 + 4 * h5];
        const float4 qa = *(const float4*)&bqp[0];
        const float4 qb = *(const float4*)&bqp[8];
        const float4 qc = *(const float4*)&bqp[16];
        const float4 qd = *(const float4*)&bqp[24];
        qv = floatx16{qa.x,qa.y,qa.z,qa.w, qb.x,qb.y,qb.z,qb.w,
                      qc.x,qc.y,qc.z,qc.w, qd.x,qd.y,qd.z,qd.w};
        const int hrow = (5 + ci) * 18 + e + 1;
        const int hb = hrow * 64, xr = hrow & 7;
        const short8_t b0 = *(const short8_t*)&HnS[hb + (((0 + h5) ^ xr) << 3)];
        const short8_t b1 = *(const short8_t*)&HnS[hb + (((2 + h5) ^ xr) << 3)];
        const short8_t b2 = *(const short8_t*)&HnS[hb + (((4 + h5) ^ xr) << 3)];
        const short8_t b3 = *(const short8_t*)&HnS[hb + (((6 + h5) ^ xr) << 3)];
        const short8_t* wqp = (const short8_t*)&wqB[(hp * 256 + lane) * 8];
        qv = __builtin_amdgcn_mfma_f32_32x32x16_bf16(wqp[0],   b0, qv, 0, 0, 0);
        qv = __builtin_amdgcn_mfma_f32_32x32x16_bf16(wqp[64],  b1, qv, 0, 0, 0);
        qv = __builtin_amdgcn_mfma_f32_32x32x16_bf16(wqp[128], b2, qv, 0, 0, 0);
        qv = __builtin_amdgcn_mfma_f32_32x32x16_bf16(wqp[192], b3, qv, 0, 0, 0);
    }

    // ---- fused K/V pass over this wave's m-subset ----
    floatx16 o = {0,0,0,0, 0,0,0,0, 0,0,0,0, 0,0,0,0};
    float ssA = 0.f, ssB = 0.f;

    const int mstart = g4 * 7;
    const int mend   = (g4 == 3) ? 27 : mstart + 7;
    for (int m = mstart; m < mend; ++m) {
        const int t  = (m * 57) >> 9;          // m/9 for m<27
        const int sp = m - 9 * t;
        const int di = (sp * 11) >> 5;         // sp/3 for sp<9
        const int dj = sp - 3 * di;
        if (!((amask >> di) & 1u)) continue;

        const int hrow = (di * 4 + dj) * 18 + t + elane;
        const int hb = hrow * 64, xr = hrow & 7;
        const short8_t b0 = *(const short8_t*)&HnS[hb + (((0 + h5) ^ xr) << 3)];
        const short8_t b1 = *(const short8_t*)&HnS[hb + (((2 + h5) ^ xr) << 3)];
        const short8_t b2 = *(const short8_t*)&HnS[hb + (((4 + h5) ^ xr) << 3)];
        const short8_t b3 = *(const short8_t*)&HnS[hb + (((6 + h5) ^ xr) << 3)];

        const short8_t* wkp = (const short8_t*)&wkB[m * 4096 + (hp * 256 + lane) * 8];
        const float* bkp = &bk[m * 64 + hp * 32 + 4 * h5];
        const float4 ka = *(const float4*)&bkp[0];
        const float4 kb = *(const float4*)&bkp[8];
        const float4 kc = *(const float4*)&bkp[16];
        const float4 kd = *(const float4*)&bkp[24];
        floatx16 kacc = floatx16{ka.x,ka.y,ka.z,ka.w, kb.x,kb.y,kb.z,kb.w,
                                 kc.x,kc.y,kc.z,kc.w, kd.x,kd.y,kd.z,kd.w};
        kacc = __builtin_amdgcn_mfma_f32_32x32x16_bf16(wkp[0],   b0, kacc, 0, 0, 0);
        kacc = __builtin_amdgcn_mfma_f32_32x32x16_bf16(wkp[64],  b1, kacc, 0, 0, 0);
        kacc = __builtin_amdgcn_mfma_f32_32x32x16_bf16(wkp[128], b2, kacc, 0, 0, 0);
        kacc = __builtin_amdgcn_mfma_f32_32x32x16_bf16(wkp[192], b3, kacc, 0, 0, 0);

        const short8_t* wvp = (const short8_t*)&wvB[m * 4096 + (hp * 256 + lane) * 8];
        const float* bvp = &bv[m * 64 + hp * 32 + 4 * h5];
        const float4 va0 = *(const float4*)&bvp[0];
        const float4 va1 = *(const float4*)&bvp[8];
        const float4 va2 = *(const float4*)&bvp[16];
        const float4 va3 = *(const float4*)&bvp[24];
        floatx16 vacc = floatx16{va0.x,va0.y,va0.z,va0.w, va1.x,va1.y,va1.z,va1.w,
                                 va2.x,va2.y,va2.z,va2.w, va3.x,va3.y,va3.z,va3.w};
        vacc = __builtin_amdgcn_mfma_f32_32x32x16_bf16(wvp[0],   b0, vacc, 0, 0, 0);
        vacc = __builtin_amdgcn_mfma_f32_32x32x16_bf16(wvp[64],  b1, vacc, 0, 0, 0);
        vacc = __builtin_amdgcn_mfma_f32_32x32x16_bf16(wvp[128], b2, vacc, 0, 0, 0);
        vacc = __builtin_amdgcn_mfma_f32_32x32x16_bf16(wvp[192], b3, vacc, 0, 0, 0);

        // score: head A = regs 0..7, head B = regs 8..15 (+ partner lane half)
        float pA = kacc[0] * qv[0];
        #pragma unroll
        for (int r = 1; r < 8; ++r) pA += kacc[r] * qv[r];
        float pB = kacc[8] * qv[8];
        #pragma unroll
        for (int r = 9; r < 16; ++r) pB += kacc[r] * qv[r];
        pA = half_sum(pA);
        pB = half_sum(pB);
        const float mf = (float)((vmask >> dj) & 1u);
        const float wA = __expf(pA) * mf;
        const float wB = __expf(pB) * mf;
        ssA += wA; ssB += wB;
        #pragma unroll
        for (int r = 0; r < 8; ++r)  o[r] += wA * vacc[r];
        #pragma unroll
        for (int r = 8; r < 16; ++r) o[r] += wB * vacc[r];
    }

    // ---- 4-way merge across m-groups: two pairwise LDS rounds ----
    __syncthreads();
    float* stbuf = (float*)HnS;            // [wid][lane][20], 16B-aligned pitch
    if (g4 >= 2) {
        float* d = &stbuf[(((g4 - 2) * 2 + hp) * 64 + lane) * 20];
        *(float4*)&d[0]  = make_float4(o[0],  o[1],  o[2],  o[3]);
        *(float4*)&d[4]  = make_float4(o[4],  o[5],  o[6],  o[7]);
        *(float4*)&d[8]  = make_float4(o[8],  o[9],  o[10], o[11]);
        *(float4*)&d[12] = make_float4(o[12], o[13], o[14], o[15]);
        *(float2*)&d[16] = make_float2(ssA, ssB);
    }
    __syncthreads();
    if (g4 < 2) {
        const float* d = &stbuf[((g4 * 2 + hp) * 64 + lane) * 20];
        const float4 r0 = *(const float4*)&d[0];
        const float4 r1 = *(const float4*)&d[4];
        const float4 r2 = *(const float4*)&d[8];
        const float4 r3 = *(const float4*)&d[12];
        const float2 rs = *(const float2*)&d[16];
        o[0] += r0.x; o[1] += r0.y; o[2]  += r0.z; o[3]  += r0.w;
        o[4] += r1.x; o[5] += r1.y; o[6]  += r1.z; o[7]  += r1.w;
        o[8] += r2.x; o[9] += r2.y; o[10] += r2.z; o[11] += r2.w;
        o[12] += r3.x; o[13] += r3.y; o[14] += r3.z; o[15] += r3.w;
        ssA += rs.x; ssB += rs.y;
    }
    __syncthreads();
    if (g4 == 1) {
        float* d = &stbuf[(hp * 64 + lane) * 20];
        *(float4*)&d[0]  = make_float4(o[0],  o[1],  o[2],  o[3]);
        *(float4*)&d[4]  = make_float4(o[4],  o[5],  o[6],  o[7]);
        *(float4*)&d[8]  = make_float4(o[8],  o[9],  o[10], o[11]);
        *(float4*)&d[12] = make_float4(o[12], o[13], o[14], o[15]);
        *(float2*)&d[16] = make_float2(ssA, ssB);
    }
    __syncthreads();
    if (g4 == 0) {
        const float* d = &stbuf[(hp * 64 + lane) * 20];
        const float4 r0 = *(const float4*)&d[0];
        const float4 r1 = *(const float4*)&d[4];
        const float4 r2 = *(const float4*)&d[8];
        const float4 r3 = *(const float4*)&d[12];
        const float2 rs = *(const float2*)&d[16];
        o[0] += r0.x; o[1] += r0.y; o[2]  += r0.z; o[3]  += r0.w;
        o[4] += r1.x; o[5] += r1.y; o[6]  += r1.z; o[7]  += r1.w;
        o[8] += r2.x; o[9] += r2.y; o[10] += r2.z; o[11] += r2.w;
        o[12] += r3.x; o[13] += r3.y; o[14] += r3.z; o[15] += r3.w;
        ssA += rs.x; ssB += rs.y;
        const float invA = 1.0f / ssA;
        const float invB = 1.0f / ssB;
        #pragma unroll
        for (int r = 0; r < 8; ++r)  o[r] *= invA;
        #pragma unroll
        for (int r = 8; r < 16; ++r) o[r] *= invB;
    }

    // ---- epilogue (g4==0 waves cover all 64 channels x 32 cols) ----
    const int n = nb * 16 + e;
    if (FIRST) {
        if (g4 == 0) {
            const int cell = (n * 32 + a) * 32 + bb0 + ci;
            const float xn0 = (x[cell*3+0] - mean0) * rs0;
            const float xn1 = (x[cell*3+1] - mean1) * rs1;
            const float xn2 = (x[cell*3+2] - mean2) * rs2;
            #pragma unroll
            for (int g = 0; g < 4; ++g) {
                short4 hb4; short* hbp = (short*)&hb4;
                #pragma unroll
                for (int i = 0; i < 4; ++i) {
                    const int c = hp * 32 + g * 8 + 4 * h5 + i;
                    const float res = Waux[192+c] + xn0*Waux[c] + xn1*Waux[64+c] + xn2*Waux[128+c];
                    hbp[i] = f2bs(o[g * 4 + i] + res);
                }
                *(short4*)&hbf_out[cell * 64 + hp * 32 + g * 8 + 4 * h5] = hb4;
            }
        }
    } else {
        __syncthreads();                   // stbuf reads done; reuse LDS for hf
        float* hf = (float*)HnS;           // [32 cols][pitch 68]
        if (g4 == 0) {
            const int cell = (n * 32 + a) * 32 + bb0 + ci;
            #pragma unroll
            for (int g = 0; g < 4; ++g) {
                const short4 hb4 = *(const short4*)&hbf_in[cell * 64 + hp * 32 + g * 8 + 4 * h5];
                float4 tv = make_float4(o[g*4+0] + bs2f(hb4.x), o[g*4+1] + bs2f(hb4.y),
                                        o[g*4+2] + bs2f(hb4.z), o[g*4+3] + bs2f(hb4.w));
                *(float4*)&hf[col * 68 + hp * 32 + g * 8 + 4 * h5] = tv;
            }
        }
        __syncthreads();
        if (tid < 96) {
            int rowglob = tid / 3, f = tid - rowglob * 3;   // rowglob = ci*16 + row
            int cio = rowglob >> 4, row = rowglob & 15;
            float acc = Waux[192 + f];
            #pragma unroll 8
            for (int cc = 0; cc < 64; ++cc) acc += hf[rowglob * 68 + cc] * Waux[cc * 3 + f];
            int nn = nb * 16 + row;
            out[((nn * 32 + a) * 32 + bb0 + cio) * 3 + f] = acc;
        }
    }
}

extern "C" void kernel_launch(void* const* d_in, const int* in_sizes, int n_in,
                              void* d_out, int out_size, void* d_ws, size_t ws_size,
                              hipStream_t stream) {
    const float* x     = (const float*)d_in[0];
    const float* W_in  = (const float*)d_in[1];
    const float* b_in  = (const float*)d_in[2];
    const float* W_out = (const float*)d_in[3];
    const float* b_out = (const float*)d_in[4];
    const float* Wq    = (const float*)d_in[5];
    const float* bq    = (const float*)d_in[6];
    const float* Wk    = (const float*)d_in[7];
    const float* bk    = (const float*)d_in[8];
    const float* Wv    = (const float*)d_in[9];
    const float* bv    = (const float*)d_in[10];

    float* ws    = (float*)d_ws;
    float* sums  = ws;                          // 32 x 8 floats (BN partials)
    short* h1bf  = (short*)(ws + 256);          // 2M shorts (4 MB)
    short* wB    = h1bf + 2097152;              // 110 x 4096 bf16 (0.9 MB)
    float* out   = (float*)d_out;

    prep_kernel<<<252, 256, 0, stream>>>(Wq, Wk, Wv, wB, x, sums);

    const short* wq0 = wB;                const short* wq1 = wB + 4096;
    const short* wk0 = wB + 2 * 4096;     const short* wk1 = wB + (2 + 27) * 4096;
    const short* wv0 = wB + 56 * 4096;    const short* wv1 = wB + (56 + 27) * 4096;

    dim3 grid(16, 32, 2);
    layer_fused<true><<<grid, 512, 0, stream>>>(
        x, sums, W_in, b_in, nullptr, h1bf, nullptr, nullptr, nullptr,
        wq0, bq, wk0, bk, wv0, bv);
    layer_fused<false><<<grid, 512, 0, stream>>>(
        nullptr, nullptr, nullptr, nullptr, h1bf, nullptr, W_out, b_out, out,
        wq1, bq + 64, wk1, bk + 1728, wv1, bv + 1728);
}

// Round 4
// 143.363 us; speedup vs baseline: 1.0194x; 1.0194x over previous
//
#include <hip/hip_runtime.h>
#include <hip/hip_bf16.h>

// N=32 time, 32x32 grid, C=64 (H=4 x D=16), 3x3x3 offsets (M=27), 2 layers.
// R15 = R14 (32x32x16 MFMA, 2-cell blocks) + m-loop latency removal:
//  - branch-free body (di-validity folded into score mask; halo is zero-filled
//    so masked lanes compute finite garbage that multiplies to 0)
//  - depth-1 software pipeline of wk (ping-pong wkX/wkY, static indexing)
//  - k/v biases staged to LDS once per block; per-m C-init reads LDS (~120cy)
//    instead of per-m global float4 (L2 200-450cy on the MFMA critical path)
//  - layer-2 out-proj: 96 serial threads -> 384 threads + shfl_xor reduce
//  - __launch_bounds__(512,4): 128-VGPR budget, 2 blocks/CU. R12 lesson:
//    never force a budget below what the loop needs (spill tripwire =
//    WRITE_SIZE >> 4MB).

typedef short short8_t __attribute__((ext_vector_type(8)));
typedef float floatx16 __attribute__((ext_vector_type(16)));

__device__ __forceinline__ short f2bs(float f) {
    __hip_bfloat16 h = __float2bfloat16(f);
    return *reinterpret_cast<short*>(&h);
}
__device__ __forceinline__ float bs2f(short s) {
    union { unsigned u; float f; } v;
    v.u = ((unsigned)(unsigned short)s) << 16;
    return v.f;
}
// swizzled halo addressing: rowid in [0,216), 8 chunks of 8 shorts, pitch 64
__device__ __forceinline__ int hn_idx(int rowid, int chunk) {
    return rowid * 64 + ((chunk ^ (rowid & 7)) << 3);
}
// p(lane) + p(lane^32), all lanes (VALU pipe, no DS)
__device__ __forceinline__ float half_sum(float p) {
    float a = p, b = p;
    asm("v_permlane32_swap_b32 %0, %1" : "+v"(a), "+v"(b));
    return a + b;
}

// ---------------- prep: repack weights (32x32x16 A layout) + BN sums ----------------
__global__ void prep_kernel(const float* __restrict__ Wq, const float* __restrict__ Wk,
                            const float* __restrict__ Wv, short* __restrict__ dst,
                            const float* __restrict__ x, float* __restrict__ sums) {
    if (blockIdx.x < 220) {
        int t = blockIdx.x * 256 + threadIdx.x;
        if (t >= 110 * 512) return;
        int mat  = t >> 9;
        int rem  = t & 511;
        int hp   = rem >> 8;          // headpair: A rows hp*32..hp*32+31
        int kk   = (rem >> 6) & 3;    // K-step (16 hidden dims each)
        int lane = rem & 63;
        // A[row = hp*32 + (lane&31)][k = kk*16 + (lane>>5)*8 + j] = W[k][row]
        int krow = kk * 16 + ((lane >> 5) << 3);
        int col  = hp * 32 + (lane & 31);
        const float* W;
        if (mat < 2)       W = Wq + mat * 4096;
        else if (mat < 56) W = Wk + (mat - 2) * 4096;
        else               W = Wv + (mat - 56) * 4096;
        short8_t v;
        #pragma unroll
        for (int j = 0; j < 8; ++j) v[j] = f2bs(W[(krow + j) * 64 + col]);
        *(short8_t*)&dst[(size_t)mat * 4096 + ((hp * 4 + kk) * 64 + lane) * 8] = v;
    } else {
        int bid = blockIdx.x - 220;
        int t = bid * 256 + threadIdx.x;          // 8192 threads x 3 float4
        const float4* x4 = (const float4*)x;
        float4 v0 = x4[t * 3 + 0], v1 = x4[t * 3 + 1], v2 = x4[t * 3 + 2];
        float vv[6];
        vv[0] = v0.x + v0.w + v1.z + v2.y;
        vv[1] = v0.y + v1.x + v1.w + v2.z;
        vv[2] = v0.z + v1.y + v2.x + v2.w;
        vv[3] = v0.x*v0.x + v0.w*v0.w + v1.z*v1.z + v2.y*v2.y;
        vv[4] = v0.y*v0.y + v1.x*v1.x + v1.w*v1.w + v2.z*v2.z;
        vv[5] = v0.z*v0.z + v1.y*v1.y + v2.x*v2.x + v2.w*v2.w;
        #pragma unroll
        for (int i = 0; i < 6; ++i) {
            #pragma unroll
            for (int off = 1; off < 64; off <<= 1) vv[i] += __shfl_xor(vv[i], off);
        }
        __shared__ float part[4][6];
        if ((threadIdx.x & 63) == 0) {
            #pragma unroll
            for (int i = 0; i < 6; ++i) part[threadIdx.x >> 6][i] = vv[i];
        }
        __syncthreads();
        if (threadIdx.x < 6)
            sums[bid * 8 + threadIdx.x] = part[0][threadIdx.x] + part[1][threadIdx.x] +
                                          part[2][threadIdx.x] + part[3][threadIdx.x];
    }
}

// ---------------- fused attention layer ----------------
// grid (b=16, a=32, nb=2); block 512 = 8 waves; wave = g4*2 + hp;
// hp = headpair (channels hp*32..+31); g4 = m-group: [0,7),[7,14),[14,21),[21,27).
// lane: col = lane&31 -> (ci = col>>4 cell, e = col&15 time row); h5 = lane>>5.
template <bool FIRST>
__global__ __launch_bounds__(512, 4)
void layer_fused(const float* __restrict__ x, const float* __restrict__ sums,
                 const float* __restrict__ W_in, const float* __restrict__ b_in,
                 const short* __restrict__ hbf_in, short* __restrict__ hbf_out,
                 const float* __restrict__ Wout, const float* __restrict__ bout,
                 float* __restrict__ out,
                 const short* __restrict__ wqB, const float* __restrict__ bq,
                 const short* __restrict__ wkB, const float* __restrict__ bk,
                 const short* __restrict__ wvB, const float* __restrict__ bv) {
    __shared__ short HnS[216 * 64];   // 27.6 KB halo; reused for merge + hf
    __shared__ float BiasS[3456];     // 13.8 KB: [m][k|v][64ch]
    __shared__ float Waux[256];
    __shared__ float bn6[6];

    const int tid = threadIdx.x;
    const int bb0 = blockIdx.x * 2, a = blockIdx.y, nb = blockIdx.z;

    if (FIRST) {
        if (tid < 3) {
            float s = 0.f, qq = 0.f;
            #pragma unroll
            for (int p = 0; p < 32; ++p) { s += sums[p * 8 + tid]; qq += sums[p * 8 + 3 + tid]; }
            float mean = s * (1.f / 32768.f);
            float var  = qq * (1.f / 32768.f) - mean * mean;
            bn6[tid]     = mean;
            bn6[3 + tid] = rsqrtf(var + 1e-5f);
        }
        if (tid < 192)      Waux[tid] = W_in[tid];
        else if (tid < 256) Waux[tid] = b_in[tid - 192];
    } else {
        if (tid < 192)      Waux[tid] = Wout[tid];
        else if (tid < 195) Waux[tid] = bout[tid - 192];
    }
    __syncthreads();

    float mean0 = 0, mean1 = 0, mean2 = 0, rs0 = 0, rs1 = 0, rs2 = 0;
    if (FIRST) {
        mean0 = bn6[0]; mean1 = bn6[1]; mean2 = bn6[2];
        rs0 = bn6[3]; rs1 = bn6[4]; rs2 = bn6[5];
    }

    // ---- stage biases: BiasS[m*128 + (k?0:64) + ch] ----
    for (int id = tid; id < 3456; id += 512) {
        const int half = (id >= 1728) ? 1 : 0;
        const int j = id - half * 1728;
        const float* src = half ? &bv[j] : &bk[j];
        BiasS[((j >> 6) << 7) + (half << 6) + (j & 63)] = *src;
    }

    // ---- stage halo: 216 rows x 8 chunks of 8 bf16 ----
    for (int id = tid; id < 1728; id += 512) {
        int rowid = id >> 3, cc = id & 7;
        int r = rowid % 18;
        int rw = rowid / 18;
        int spa = rw >> 2, jcol = rw & 3;
        int aa = a + spa - 1, bb = bb0 + jcol - 1;
        int n  = nb * 16 + r - 1;
        short8_t v = {0, 0, 0, 0, 0, 0, 0, 0};
        if ((unsigned)n < 32u && (unsigned)aa < 32u && (unsigned)bb < 32u) {
            int cell = (n * 32 + aa) * 32 + bb;
            if (FIRST) {
                float xn0 = (x[cell*3+0] - mean0) * rs0;
                float xn1 = (x[cell*3+1] - mean1) * rs1;
                float xn2 = (x[cell*3+2] - mean2) * rs2;
                #pragma unroll
                for (int j = 0; j < 8; ++j) {
                    int c = cc * 8 + j;
                    float h = Waux[192+c] + xn0*Waux[c] + xn1*Waux[64+c] + xn2*Waux[128+c];
                    v[j] = f2bs(h);
                }
            } else {
                v = *(const short8_t*)&hbf_in[cell * 64 + cc * 8];
            }
        }
        *(short8_t*)&HnS[hn_idx(rowid, cc)] = v;
    }
    __syncthreads();

    const int lane = tid & 63;
    const int wv8  = tid >> 6;
    const int hp   = wv8 & 1;        // headpair
    const int g4   = wv8 >> 1;       // m-group
    const int col  = lane & 31;
    const int e    = col & 15;
    const int ci   = col >> 4;
    const int h5   = lane >> 5;

    // spatial validity
    unsigned amask = 0;
    #pragma unroll
    for (int d = 0; d < 3; ++d) if ((unsigned)(a + d - 1) < 32u) amask |= 1u << d;
    const bool vbL = (unsigned)(bb0 - 1) < 32u;   // jcol 0
    const bool vbR = (unsigned)(bb0 + 2) < 32u;   // jcol 3
    const unsigned vmask = (ci == 0) ? ((vbL ? 1u : 0u) | 2u | 4u)
                                     : (1u | 2u | (vbR ? 4u : 0u));

    const int elane = e + ci * 18;   // per-lane halo-row offset

    // ---- Q projection (center cell per col): 4 chained 32x32x16 MFMAs ----
    floatx16 qv;
    {
        const float* bqp = &bq[hp * 32 + 4 * h5];
        const float4 qa = *(const float4*)&bqp[0];
        const float4 qb = *(const float4*)&bqp[8];
        const float4 qc = *(const float4*)&bqp[16];
        const float4 qd = *(const float4*)&bqp[24];
        qv = floatx16{qa.x,qa.y,qa.z,qa.w, qb.x,qb.y,qb.z,qb.w,
                      qc.x,qc.y,qc.z,qc.w, qd.x,qd.y,qd.z,qd.w};
        const int hrow = (5 + ci) * 18 + e + 1;
        const int hb = hrow * 64, xr = hrow & 7;
        const short8_t b0 = *(const short8_t*)&HnS[hb + (((0 + h5) ^ xr) << 3)];
        const short8_t b1 = *(const short8_t*)&HnS[hb + (((2 + h5) ^ xr) << 3)];
        const short8_t b2 = *(const short8_t*)&HnS[hb + (((4 + h5) ^ xr) << 3)];
        const short8_t b3 = *(const short8_t*)&HnS[hb + (((6 + h5) ^ xr) << 3)];
        const short8_t* wqp = (const short8_t*)&wqB[(hp * 256 + lane) * 8];
        qv = __builtin_amdgcn_mfma_f32_32x32x16_bf16(wqp[0],   b0, qv, 0, 0, 0);
        qv = __builtin_amdgcn_mfma_f32_32x32x16_bf16(wqp[64],  b1, qv, 0, 0, 0);
        qv = __builtin_amdgcn_mfma_f32_32x32x16_bf16(wqp[128], b2, qv, 0, 0, 0);
        qv = __builtin_amdgcn_mfma_f32_32x32x16_bf16(wqp[192], b3, qv, 0, 0, 0);
    }

    // ---- fused K/V pass, branch-free, wk software-pipelined depth 1 ----
    floatx16 o = {0,0,0,0, 0,0,0,0, 0,0,0,0, 0,0,0,0};
    float ssA = 0.f, ssB = 0.f;

    const int mstart = g4 * 7;
    const int mend   = (g4 == 3) ? 27 : mstart + 7;

    const short* wkBase = wkB + hp * 2048 + lane * 8;
    const short* wvBase = wvB + hp * 2048 + lane * 8;

    short8_t wkX[4], wkY[4];
    #pragma unroll
    for (int j = 0; j < 4; ++j)
        wkX[j] = *(const short8_t*)&wkBase[mstart * 4096 + j * 512];

    auto body = [&](short8_t (&wkc)[4], short8_t (&wkn)[4], const int m) {
        const int mn = (m + 1 < mend) ? (m + 1) : m;
        const int t  = (m * 57) >> 9;          // m/9 for m<27
        const int sp = m - 9 * t;
        const int di = (sp * 11) >> 5;         // sp/3 for sp<9
        const int dj = sp - 3 * di;

        // halo LDS reads for current m
        const int hrow = (di * 4 + dj) * 18 + t + elane;
        const int hb = hrow * 64, xr = hrow & 7;
        const short8_t b0 = *(const short8_t*)&HnS[hb + (((0 + h5) ^ xr) << 3)];
        const short8_t b1 = *(const short8_t*)&HnS[hb + (((2 + h5) ^ xr) << 3)];
        const short8_t b2 = *(const short8_t*)&HnS[hb + (((4 + h5) ^ xr) << 3)];
        const short8_t b3 = *(const short8_t*)&HnS[hb + (((6 + h5) ^ xr) << 3)];

        // biases from LDS straight into the accumulators
        const float* bks = &BiasS[(m << 7) + (hp << 5) + (h5 << 2)];
        const float4 ka = *(const float4*)&bks[0];
        const float4 kb = *(const float4*)&bks[8];
        const float4 kc = *(const float4*)&bks[16];
        const float4 kd = *(const float4*)&bks[24];
        const float4 va0 = *(const float4*)&bks[64];
        const float4 va1 = *(const float4*)&bks[72];
        const float4 va2 = *(const float4*)&bks[80];
        const float4 va3 = *(const float4*)&bks[88];

        // current-m V weights (first use after the K chain)
        const short8_t wv0 = *(const short8_t*)&wvBase[m * 4096 + 0];
        const short8_t wv1 = *(const short8_t*)&wvBase[m * 4096 + 512];
        const short8_t wv2 = *(const short8_t*)&wvBase[m * 4096 + 1024];
        const short8_t wv3 = *(const short8_t*)&wvBase[m * 4096 + 1536];

        // prefetch next-m K weights (consumed next body call)
        #pragma unroll
        for (int j = 0; j < 4; ++j)
            wkn[j] = *(const short8_t*)&wkBase[mn * 4096 + j * 512];

        floatx16 kacc = floatx16{ka.x,ka.y,ka.z,ka.w, kb.x,kb.y,kb.z,kb.w,
                                 kc.x,kc.y,kc.z,kc.w, kd.x,kd.y,kd.z,kd.w};
        kacc = __builtin_amdgcn_mfma_f32_32x32x16_bf16(wkc[0], b0, kacc, 0, 0, 0);
        kacc = __builtin_amdgcn_mfma_f32_32x32x16_bf16(wkc[1], b1, kacc, 0, 0, 0);
        kacc = __builtin_amdgcn_mfma_f32_32x32x16_bf16(wkc[2], b2, kacc, 0, 0, 0);
        kacc = __builtin_amdgcn_mfma_f32_32x32x16_bf16(wkc[3], b3, kacc, 0, 0, 0);

        floatx16 vacc = floatx16{va0.x,va0.y,va0.z,va0.w, va1.x,va1.y,va1.z,va1.w,
                                 va2.x,va2.y,va2.z,va2.w, va3.x,va3.y,va3.z,va3.w};
        vacc = __builtin_amdgcn_mfma_f32_32x32x16_bf16(wv0, b0, vacc, 0, 0, 0);
        vacc = __builtin_amdgcn_mfma_f32_32x32x16_bf16(wv1, b1, vacc, 0, 0, 0);
        vacc = __builtin_amdgcn_mfma_f32_32x32x16_bf16(wv2, b2, vacc, 0, 0, 0);
        vacc = __builtin_amdgcn_mfma_f32_32x32x16_bf16(wv3, b3, vacc, 0, 0, 0);

        // score: head A = regs 0..7, head B = regs 8..15 (+ partner lane half)
        float pA = kacc[0] * qv[0];
        #pragma unroll
        for (int r = 1; r < 8; ++r) pA += kacc[r] * qv[r];
        float pB = kacc[8] * qv[8];
        #pragma unroll
        for (int r = 9; r < 16; ++r) pB += kacc[r] * qv[r];
        pA = half_sum(pA);
        pB = half_sum(pB);
        const float mf = (float)(((amask >> di) & (vmask >> dj)) & 1u);
        const float wA = __expf(pA) * mf;
        const float wB = __expf(pB) * mf;
        ssA += wA; ssB += wB;
        #pragma unroll
        for (int r = 0; r < 8; ++r)  o[r] += wA * vacc[r];
        #pragma unroll
        for (int r = 8; r < 16; ++r) o[r] += wB * vacc[r];
    };

    for (int m = mstart; m < mend; m += 2) {
        body(wkX, wkY, m);
        if (m + 1 < mend) body(wkY, wkX, m + 1);
    }

    // ---- 4-way merge across m-groups: two pairwise LDS rounds ----
    __syncthreads();
    float* stbuf = (float*)HnS;            // [wid][lane][20], 16B-aligned pitch
    if (g4 >= 2) {
        float* d = &stbuf[(((g4 - 2) * 2 + hp) * 64 + lane) * 20];
        *(float4*)&d[0]  = make_float4(o[0],  o[1],  o[2],  o[3]);
        *(float4*)&d[4]  = make_float4(o[4],  o[5],  o[6],  o[7]);
        *(float4*)&d[8]  = make_float4(o[8],  o[9],  o[10], o[11]);
        *(float4*)&d[12] = make_float4(o[12], o[13], o[14], o[15]);
        *(float2*)&d[16] = make_float2(ssA, ssB);
    }
    __syncthreads();
    if (g4 < 2) {
        const float* d = &stbuf[((g4 * 2 + hp) * 64 + lane) * 20];
        const float4 r0 = *(const float4*)&d[0];
        const float4 r1 = *(const float4*)&d[4];
        const float4 r2 = *(const float4*)&d[8];
        const float4 r3 = *(const float4*)&d[12];
        const float2 rs = *(const float2*)&d[16];
        o[0] += r0.x; o[1] += r0.y; o[2]  += r0.z; o[3]  += r0.w;
        o[4] += r1.x; o[5] += r1.y; o[6]  += r1.z; o[7]  += r1.w;
        o[8] += r2.x; o[9] += r2.y; o[10] += r2.z; o[11] += r2.w;
        o[12] += r3.x; o[13] += r3.y; o[14] += r3.z; o[15] += r3.w;
        ssA += rs.x; ssB += rs.y;
    }
    __syncthreads();
    if (g4 == 1) {
        float* d = &stbuf[(hp * 64 + lane) * 20];
        *(float4*)&d[0]  = make_float4(o[0],  o[1],  o[2],  o[3]);
        *(float4*)&d[4]  = make_float4(o[4],  o[5],  o[6],  o[7]);
        *(float4*)&d[8]  = make_float4(o[8],  o[9],  o[10], o[11]);
        *(float4*)&d[12] = make_float4(o[12], o[13], o[14], o[15]);
        *(float2*)&d[16] = make_float2(ssA, ssB);
    }
    __syncthreads();
    if (g4 == 0) {
        const float* d = &stbuf[(hp * 64 + lane) * 20];
        const float4 r0 = *(const float4*)&d[0];
        const float4 r1 = *(const float4*)&d[4];
        const float4 r2 = *(const float4*)&d[8];
        const float4 r3 = *(const float4*)&d[12];
        const float2 rs = *(const float2*)&d[16];
        o[0] += r0.x; o[1] += r0.y; o[2]  += r0.z; o[3]  += r0.w;
        o[4] += r1.x; o[5] += r1.y; o[6]  += r1.z; o[7]  += r1.w;
        o[8] += r2.x; o[9] += r2.y; o[10] += r2.z; o[11] += r2.w;
        o[12] += r3.x; o[13] += r3.y; o[14] += r3.z; o[15] += r3.w;
        ssA += rs.x; ssB += rs.y;
        const float invA = 1.0f / ssA;
        const float invB = 1.0f / ssB;
        #pragma unroll
        for (int r = 0; r < 8; ++r)  o[r] *= invA;
        #pragma unroll
        for (int r = 8; r < 16; ++r) o[r] *= invB;
    }

    // ---- epilogue (g4==0 waves cover all 64 channels x 32 cols) ----
    const int n = nb * 16 + e;
    if (FIRST) {
        if (g4 == 0) {
            const int cell = (n * 32 + a) * 32 + bb0 + ci;
            const float xn0 = (x[cell*3+0] - mean0) * rs0;
            const float xn1 = (x[cell*3+1] - mean1) * rs1;
            const float xn2 = (x[cell*3+2] - mean2) * rs2;
            #pragma unroll
            for (int g = 0; g < 4; ++g) {
                short4 hb4; short* hbp = (short*)&hb4;
                #pragma unroll
                for (int i = 0; i < 4; ++i) {
                    const int c = hp * 32 + g * 8 + 4 * h5 + i;
                    const float res = Waux[192+c] + xn0*Waux[c] + xn1*Waux[64+c] + xn2*Waux[128+c];
                    hbp[i] = f2bs(o[g * 4 + i] + res);
                }
                *(short4*)&hbf_out[cell * 64 + hp * 32 + g * 8 + 4 * h5] = hb4;
            }
        }
    } else {
        __syncthreads();                   // stbuf reads done; reuse LDS for hf
        float* hf = (float*)HnS;           // [32 cols][pitch 68]
        if (g4 == 0) {
            const int cell = (n * 32 + a) * 32 + bb0 + ci;
            #pragma unroll
            for (int g = 0; g < 4; ++g) {
                const short4 hb4 = *(const short4*)&hbf_in[cell * 64 + hp * 32 + g * 8 + 4 * h5];
                float4 tv = make_float4(o[g*4+0] + bs2f(hb4.x), o[g*4+1] + bs2f(hb4.y),
                                        o[g*4+2] + bs2f(hb4.z), o[g*4+3] + bs2f(hb4.w));
                *(float4*)&hf[col * 68 + hp * 32 + g * 8 + 4 * h5] = tv;
            }
        }
        __syncthreads();
        // out-proj: 96 outputs x 4 partial-threads (16 channels each) + shfl reduce
        if (tid < 384) {
            const int oid = tid >> 2, part = tid & 3;
            const int rowglob = oid / 3, f = oid - rowglob * 3;
            const int cstart = part << 4;
            float acc = 0.f;
            #pragma unroll
            for (int cc = 0; cc < 16; ++cc)
                acc += hf[rowglob * 68 + cstart + cc] * Waux[(cstart + cc) * 3 + f];
            acc += __shfl_xor(acc, 1);
            acc += __shfl_xor(acc, 2);
            if (part == 0) {
                const int cio = rowglob >> 4, row = rowglob & 15;
                out[(((nb * 16 + row) * 32 + a) * 32 + bb0 + cio) * 3 + f] =
                    acc + Waux[192 + f];
            }
        }
    }
}

extern "C" void kernel_launch(void* const* d_in, const int* in_sizes, int n_in,
                              void* d_out, int out_size, void* d_ws, size_t ws_size,
                              hipStream_t stream) {
    const float* x     = (const float*)d_in[0];
    const float* W_in  = (const float*)d_in[1];
    const float* b_in  = (const float*)d_in[2];
    const float* W_out = (const float*)d_in[3];
    const float* b_out = (const float*)d_in[4];
    const float* Wq    = (const float*)d_in[5];
    const float* bq    = (const float*)d_in[6];
    const float* Wk    = (const float*)d_in[7];
    const float* bk    = (const float*)d_in[8];
    const float* Wv    = (const float*)d_in[9];
    const float* bv    = (const float*)d_in[10];

    float* ws    = (float*)d_ws;
    float* sums  = ws;                          // 32 x 8 floats (BN partials)
    short* h1bf  = (short*)(ws + 256);          // 2M shorts (4 MB)
    short* wB    = h1bf + 2097152;              // 110 x 4096 bf16 (0.9 MB)
    float* out   = (float*)d_out;

    prep_kernel<<<252, 256, 0, stream>>>(Wq, Wk, Wv, wB, x, sums);

    const short* wq0 = wB;                const short* wq1 = wB + 4096;
    const short* wk0 = wB + 2 * 4096;     const short* wk1 = wB + (2 + 27) * 4096;
    const short* wv0 = wB + 56 * 4096;    const short* wv1 = wB + (56 + 27) * 4096;

    dim3 grid(16, 32, 2);
    layer_fused<true><<<grid, 512, 0, stream>>>(
        x, sums, W_in, b_in, nullptr, h1bf, nullptr, nullptr, nullptr,
        wq0, bq, wk0, bk, wv0, bv);
    layer_fused<false><<<grid, 512, 0, stream>>>(
        nullptr, nullptr, nullptr, nullptr, h1bf, nullptr, W_out, b_out, out,
        wq1, bq + 64, wk1, bk + 1728, wv1, bv + 1728);
}